// Round 7
// baseline (7006.197 us; speedup 1.0000x reference)
//
#include <hip/hip_runtime.h>

// CustomGRU: B=256, T=1024, I=128, H=256.  out = concat(output[B,T,H], h_last[B,H]) f32.
//
// All-f32 pipeline. Phase 2 pairs WGs (2 per batch-pair) with W_hh register-resident;
// cross-WG h exchange via parity-double-buffered packed (version<<32|value) u64 slots
// (agent-scope atomics).
//
// R7 change: W_hh per-thread weights are 192 NAMED SCALARS (macro-generated), not a
// float[192]. R3-R6 showed the array was never SROA-promoted (runtime-indexed init
// loop runs before unroll) and the step loop re-loaded whh from L2 every step
// (393KB/step/WG -> L2-BW-bound ~7000cyc/step). Named scalars + literal-index init +
// per-value opaque asm defs make register residency independent of SROA/GVN.

#define B_SZ 256
#define T_SZ 1024
#define H_SZ 256
#define G3   768
#define NPAIR 128
#define SPIN_MAX (1 << 28)

static __device__ __forceinline__ size_t xidx(int pair, int role, int parity, int b2, int j) {
    return ((((size_t)pair * 2 + role) * 2 + parity) * 2 + b2) * 128 + j;
}

__device__ __forceinline__ float qadd1(float x) {
    int v = __builtin_amdgcn_update_dpp(0, __float_as_int(x), 0xB1, 0xF, 0xF, true); // quad_perm [1,0,3,2]
    return x + __int_as_float(v);
}
__device__ __forceinline__ float qadd2(float x) {
    int v = __builtin_amdgcn_update_dpp(0, __float_as_int(x), 0x4E, 0xF, 0xF, true); // quad_perm [2,3,0,1]
    return x + __int_as_float(v);
}
__device__ __forceinline__ float qsum(float x) { return qadd2(qadd1(x)); }

// ---------------- prep: exchange slots <- (version 0, h0), both parities ----------------
__global__ void prep_kernel(const float* __restrict__ h0,
                            unsigned long long* __restrict__ xch) {
    int tid = blockIdx.x * blockDim.x + threadIdx.x;
    if (tid < B_SZ * H_SZ) {
        int b = tid >> 8, U = tid & 255;
        int pair = b >> 1, b2 = b & 1, role = U >> 7, j = U & 127;
        unsigned long long val = (unsigned long long)__float_as_uint(h0[tid]);
        xch[xidx(pair, role, 0, b2, j)] = val;
        xch[xidx(pair, role, 1, b2, j)] = val;
    }
}

// ---------------- phase 1: gx = x @ W_ih^T, pure f32 ----------------
__global__ __launch_bounds__(256) void gemm_x_kernel(
    const float* __restrict__ x, const float* __restrict__ wih,
    float* __restrict__ gx, int c, int tcShift)
{
    __shared__ __align__(16) float xs[64 * 128];
    const int TC = 1 << tcShift;
    const int t  = threadIdx.x;
    const int bx = blockIdx.x, by = blockIdx.y;

#pragma unroll
    for (int i = 0; i < 8; ++i) {
        int f4 = t + i * 256;
        int r  = f4 >> 5, c4 = f4 & 31;
        int rho = bx * 64 + r;
        int b = rho >> tcShift, u = rho & (TC - 1);
        float4 v = *(const float4*)(x + ((size_t)b * T_SZ + (size_t)c * TC + u) * 128 + c4 * 4);
        *(float4*)(xs + r * 128 + c4 * 4) = v;
    }
    __syncthreads();

    const int gl = (t & 31) * 4;
    const int rl = t >> 5;
    float acc[8][4];
#pragma unroll
    for (int i = 0; i < 8; ++i)
#pragma unroll
        for (int jj = 0; jj < 4; ++jj) acc[i][jj] = 0.f;

    const float* w0 = wih + (size_t)(by * 128 + gl) * 128;
#pragma unroll 4
    for (int k4 = 0; k4 < 32; ++k4) {
        float4 wv[4];
#pragma unroll
        for (int gi = 0; gi < 4; ++gi)
            wv[gi] = *(const float4*)(w0 + (size_t)gi * 128 + k4 * 4);
#pragma unroll
        for (int rr = 0; rr < 8; ++rr) {
            float4 xv = *(const float4*)(xs + (rl + rr * 8) * 128 + k4 * 4);
#pragma unroll
            for (int gi = 0; gi < 4; ++gi) {
                acc[rr][gi] = fmaf(xv.x, wv[gi].x,
                              fmaf(xv.y, wv[gi].y,
                              fmaf(xv.z, wv[gi].z,
                              fmaf(xv.w, wv[gi].w, acc[rr][gi]))));
            }
        }
    }
#pragma unroll
    for (int rr = 0; rr < 8; ++rr) {
        int rho = bx * 64 + rl + rr * 8;
        float4 o; o.x = acc[rr][0]; o.y = acc[rr][1]; o.z = acc[rr][2]; o.w = acc[rr][3];
        *(float4*)(gx + (size_t)rho * G3 + by * 128 + gl) = o;
    }
}

// ================= macro machinery for 192 named weight scalars =================
#define REP64(M, Q) \
M(Q,0)  M(Q,1)  M(Q,2)  M(Q,3)  M(Q,4)  M(Q,5)  M(Q,6)  M(Q,7)  \
M(Q,8)  M(Q,9)  M(Q,10) M(Q,11) M(Q,12) M(Q,13) M(Q,14) M(Q,15) \
M(Q,16) M(Q,17) M(Q,18) M(Q,19) M(Q,20) M(Q,21) M(Q,22) M(Q,23) \
M(Q,24) M(Q,25) M(Q,26) M(Q,27) M(Q,28) M(Q,29) M(Q,30) M(Q,31) \
M(Q,32) M(Q,33) M(Q,34) M(Q,35) M(Q,36) M(Q,37) M(Q,38) M(Q,39) \
M(Q,40) M(Q,41) M(Q,42) M(Q,43) M(Q,44) M(Q,45) M(Q,46) M(Q,47) \
M(Q,48) M(Q,49) M(Q,50) M(Q,51) M(Q,52) M(Q,53) M(Q,54) M(Q,55) \
M(Q,56) M(Q,57) M(Q,58) M(Q,59) M(Q,60) M(Q,61) M(Q,62) M(Q,63)

#define DECL_W(Q, I) float w##Q##_##I;
#define PIN_W(Q, I)  asm volatile("" : "+v"(w##Q##_##I));

// load 4 consecutive weights from pointer wrQ at offset OFF into named scalars
#define INIT4(Q, I0, I1, I2, I3, OFF) { \
    float4 tv = *(const float4*)(wr##Q + (OFF)); \
    w##Q##_##I0 = tv.x; w##Q##_##I1 = tv.y; w##Q##_##I2 = tv.z; w##Q##_##I3 = tv.w; }

#define INIT_Q(Q) \
    INIT4(Q, 0, 1, 2, 3,    kO + 0)  INIT4(Q, 4, 5, 6, 7,    kO + 4)  \
    INIT4(Q, 8, 9, 10,11,   kO + 8)  INIT4(Q, 12,13,14,15,   kO + 12) \
    INIT4(Q, 16,17,18,19,   kO + 16) INIT4(Q, 20,21,22,23,   kO + 20) \
    INIT4(Q, 24,25,26,27,   kO + 24) INIT4(Q, 28,29,30,31,   kO + 28) \
    INIT4(Q, 32,33,34,35,   kP + 0)  INIT4(Q, 36,37,38,39,   kP + 4)  \
    INIT4(Q, 40,41,42,43,   kP + 8)  INIT4(Q, 44,45,46,47,   kP + 12) \
    INIT4(Q, 48,49,50,51,   kP + 16) INIT4(Q, 52,53,54,55,   kP + 20) \
    INIT4(Q, 56,57,58,59,   kP + 24) INIT4(Q, 60,61,62,63,   kP + 28)

// one h-float4 (2 units x 2 batches) against weight pair (J0,J1) of all 3 gates
#define MV(I2, J0, J1) { \
    float4 hv = *(const float4*)(hb + 4 * (I2)); \
    a00 = fmaf(w0_##J0, hv.x, a00); a01 = fmaf(w0_##J0, hv.y, a01); \
    a00 = fmaf(w0_##J1, hv.z, a00); a01 = fmaf(w0_##J1, hv.w, a01); \
    a10 = fmaf(w1_##J0, hv.x, a10); a11 = fmaf(w1_##J0, hv.y, a11); \
    a10 = fmaf(w1_##J1, hv.z, a10); a11 = fmaf(w1_##J1, hv.w, a11); \
    a20 = fmaf(w2_##J0, hv.x, a20); a21 = fmaf(w2_##J0, hv.y, a21); \
    a20 = fmaf(w2_##J1, hv.z, a20); a21 = fmaf(w2_##J1, hv.w, a21); }

// ---------------- phase 2: paired f32 recurrence ----------------
__global__ __launch_bounds__(512)
__attribute__((amdgpu_waves_per_eu(2, 2)))
void gru_kernel(
    const float* __restrict__ gx, const float* __restrict__ whh,
    const float* __restrict__ bih, const float* __restrict__ bhh,
    unsigned long long* __restrict__ xch, float* __restrict__ out,
    int gbase, int tc, int isLast)
{
    __shared__ __align__(16) float hl[4 * 132];

    const int t   = threadIdx.x;
    const int bid = blockIdx.x;
    const int pair = (bid >> 4) * 8 + (bid & 7);
    const int ro   = (bid >> 3) & 1;
    const int roflip = ro << 7;
    const int b0 = pair * 2;

    const int wv = t >> 6, l = t & 63, g = l >> 2, p = l & 3;
    const int jo = wv * 16 + g;
    const int ju = roflip + jo;

    // ---- 192 named register-resident weights ----
    REP64(DECL_W, 0) REP64(DECL_W, 1) REP64(DECL_W, 2)
    {
        const int kO = roflip + 32 * p;
        const int kP = (roflip ^ 128) + 32 * p;
        const float* wr0 = whh + (size_t)(0 * 256 + ju) * H_SZ;
        const float* wr1 = whh + (size_t)(1 * 256 + ju) * H_SZ;
        const float* wr2 = whh + (size_t)(2 * 256 + ju) * H_SZ;
        INIT_Q(0) INIT_Q(1) INIT_Q(2)
    }
    // opaque defs: non-rematerializable, must stay live (in regs) across the loop
    REP64(PIN_W, 0) REP64(PIN_W, 1) REP64(PIN_W, 2)

    const float bsr = bih[ju]       + bhh[ju];
    const float bsz = bih[256 + ju] + bhh[256 + ju];
    const float bsn = bih[512 + ju] + bhh[512 + ju];

    // ---- restore h(gbase) ----
    {
        int rr = t >> 8, b2 = (t >> 7) & 1, jj = t & 127;
        unsigned long long* slot = xch + xidx(pair, rr, gbase & 1, b2, jj);
        const unsigned want = (unsigned)gbase;
        unsigned long long v = __hip_atomic_load(slot, __ATOMIC_RELAXED, __HIP_MEMORY_SCOPE_AGENT);
        int spins = 0;
        while ((unsigned)(v >> 32) != want && spins < SPIN_MAX) {
            __builtin_amdgcn_s_sleep(2);
            v = __hip_atomic_load(slot, __ATOMIC_RELAXED, __HIP_MEMORY_SCOPE_AGENT);
            ++spins;
        }
        int pos = (rr == ro)
                ? (jj >> 5) * 132 + (jj & 31) * 2 + b2
                : (jj >> 5) * 132 + (32 + (jj & 31)) * 2 + b2;
        hl[pos] = __uint_as_float((unsigned)v);
    }
    __syncthreads();

    float hold0 = hl[(jo >> 5) * 132 + (jo & 31) * 2 + 0];
    float hold1 = hl[(jo >> 5) * 132 + (jo & 31) * 2 + 1];

    const int pj = t & 127, pb2 = (t >> 7) & 1;
    const int ppos = (pj >> 5) * 132 + (32 + (pj & 31)) * 2 + pb2;
    const int prole = 1 - ro;

    const float* gr0p = gx + (size_t)b0 * tc * G3 + ju;
    const float* gr1p = gx + (size_t)(b0 + 1) * tc * G3 + ju;
    const float* hb = hl + p * 132;

    for (int u = 0; u < tc; ++u) {
        size_t go = (size_t)u * G3;
        float gxr0 = gr0p[go], gxz0 = gr0p[go + 256], gxn0 = gr0p[go + 512];
        float gxr1 = gr1p[go], gxz1 = gr1p[go + 256], gxn1 = gr1p[go + 512];

        float a00 = 0.f, a01 = 0.f, a10 = 0.f, a11 = 0.f, a20 = 0.f, a21 = 0.f;
        // -- own half (h available from previous step) --
        MV(0,0,1)   MV(1,2,3)   MV(2,4,5)   MV(3,6,7)
        MV(4,8,9)   MV(5,10,11) MV(6,12,13) MV(7,14,15)
        MV(8,16,17) MV(9,18,19) MV(10,20,21) MV(11,22,23)
        MV(12,24,25) MV(13,26,27) MV(14,28,29) MV(15,30,31)

        // -- fetch partner half h(gbase+u) (u=0 came from restore) --
        if (u > 0 && t < 256) {
            const unsigned want = (unsigned)(gbase + u);
            unsigned long long* slot = xch + xidx(pair, prole, (gbase + u) & 1, pb2, pj);
            unsigned long long v = __hip_atomic_load(slot, __ATOMIC_RELAXED, __HIP_MEMORY_SCOPE_AGENT);
            int spins = 0;
            while ((unsigned)(v >> 32) != want && spins < SPIN_MAX) {
                __builtin_amdgcn_s_sleep(2);
                v = __hip_atomic_load(slot, __ATOMIC_RELAXED, __HIP_MEMORY_SCOPE_AGENT);
                ++spins;
            }
            hl[ppos] = __uint_as_float((unsigned)v);
        }
        __syncthreads();

        // -- partner half --
        MV(16,32,33) MV(17,34,35) MV(18,36,37) MV(19,38,39)
        MV(20,40,41) MV(21,42,43) MV(22,44,45) MV(23,46,47)
        MV(24,48,49) MV(25,50,51) MV(26,52,53) MV(27,54,55)
        MV(28,56,57) MV(29,58,59) MV(30,60,61) MV(31,62,63)

        float s00 = qsum(a00), s01 = qsum(a01);
        float s10 = qsum(a10), s11 = qsum(a11);
        float s20 = qsum(a20), s21 = qsum(a21);

        float ar0 = s00 + gxr0 + bsr, ar1 = s01 + gxr1 + bsr;
        float az0 = s10 + gxz0 + bsz, az1 = s11 + gxz1 + bsz;
        float an0 = s20 + gxn0 + bsn, an1 = s21 + gxn1 + bsn;
        float r0 = 1.f / (1.f + expf(-ar0));
        float r1 = 1.f / (1.f + expf(-ar1));
        float z0 = 1.f / (1.f + expf(-az0));
        float z1 = 1.f / (1.f + expf(-az1));
        float n0 = tanhf(r0 * an0);
        float n1 = tanhf(r1 * an1);
        float hn0 = (1.f - z0) * hold0 + z0 * n0;
        float hn1 = (1.f - z1) * hold1 + z1 * n1;
        hold0 = hn0; hold1 = hn1;

        const int tg = gbase + u;
        if (p == 0) {
            hl[(jo >> 5) * 132 + (jo & 31) * 2 + 0] = hn0;
            hl[(jo >> 5) * 132 + (jo & 31) * 2 + 1] = hn1;
            size_t o0 = ((size_t)b0 * T_SZ + tg) * H_SZ + ju;
            out[o0] = hn0;
            out[o0 + (size_t)T_SZ * H_SZ] = hn1;
            if (isLast && u == tc - 1) {
                out[(size_t)B_SZ * T_SZ * H_SZ + (size_t)b0 * H_SZ + ju]       = hn0;
                out[(size_t)B_SZ * T_SZ * H_SZ + (size_t)(b0 + 1) * H_SZ + ju] = hn1;
            }
            const unsigned long long ver = (unsigned long long)(unsigned)(tg + 1) << 32;
            const int par = (tg + 1) & 1;
            __hip_atomic_store(xch + xidx(pair, ro, par, 0, jo),
                               ver | (unsigned long long)__float_as_uint(hn0),
                               __ATOMIC_RELAXED, __HIP_MEMORY_SCOPE_AGENT);
            __hip_atomic_store(xch + xidx(pair, ro, par, 1, jo),
                               ver | (unsigned long long)__float_as_uint(hn1),
                               __ATOMIC_RELAXED, __HIP_MEMORY_SCOPE_AGENT);
        }
        __syncthreads();
    }
}

// ---------------- host ----------------
extern "C" void kernel_launch(void* const* d_in, const int* in_sizes, int n_in,
                              void* d_out, int out_size, void* d_ws, size_t ws_size,
                              hipStream_t stream) {
    const float* x   = (const float*)d_in[0];
    const float* h0  = (const float*)d_in[1];
    const float* wih = (const float*)d_in[2];
    const float* whh = (const float*)d_in[3];
    const float* bih = (const float*)d_in[4];
    const float* bhh = (const float*)d_in[5];
    float* out = (float*)d_out;

    char* ws = (char*)d_ws;
    const size_t xchB = (size_t)NPAIR * 2 * 2 * 2 * 128 * 8;   // 1 MiB
    unsigned long long* xch = (unsigned long long*)ws;
    float* gxb = (float*)(ws + xchB);

    int tcShift = 10;
    while (tcShift > 0 &&
           xchB + ((size_t)G3 * 4 * B_SZ << tcShift) > ws_size) --tcShift;
    const int TC  = 1 << tcShift;
    const int nCh = T_SZ / TC;

    prep_kernel<<<dim3(256), dim3(256), 0, stream>>>(h0, xch);
    for (int c = 0; c < nCh; ++c) {
        gemm_x_kernel<<<dim3(B_SZ * TC / 64, 6), dim3(256), 0, stream>>>(
            x, wih, gxb, c, tcShift);
        gru_kernel<<<dim3(B_SZ), dim3(512), 0, stream>>>(
            gxb, whh, bih, bhh, xch, out, c * TC, TC, (c == nCh - 1) ? 1 : 0);
    }
}

// Round 8
// 6008.858 us; speedup vs baseline: 1.1660x; 1.1660x over previous
//
#include <hip/hip_runtime.h>

// CustomGRU: B=256, T=1024, I=128, H=256.  out = concat(output[B,T,H], h_last[B,H]) f32.
//
// R8: structural pivot for phase 2. R3-R7 proved this compiler will not keep ~192
// per-thread f32 weights register-resident (VGPR stuck at 128; weights re-fetched
// from L2 every step -> 7000 cyc/step L2-BW wall). New design shares weights per-CU
// via LDS instead: 32 groups x 8 WGs; WG owns 32 units (96 rows x 256 = 96KB f32 in
// LDS, loaded once) and 8 batch rows. Per step: LDS matvec (W re-read 98KB + h 262KB
// ~= 3.2k cyc, the honest LDS-BW bound), DPP 16-lane reduce (pure VALU), gates, and
// an 8-way parity-double-buffered version-slot exchange (same protocol as R3-R7,
// proven deadlock-free; group members land on one XCD via bid mod 8 == g).

#define B_SZ 256
#define T_SZ 1024
#define H_SZ 256
#define G3   768
#define NGRP 32
#define SPIN_MAX (1 << 27)

// xch slot: [group 32][parity 2][unit 256][batch-in-group 8] = 64K u64 = 512KB... 
// (32*2*256*8 = 131072 slots * 8B = 1MB)
static __device__ __forceinline__ size_t xsl(int g, int par, int u, int n) {
    return (((size_t)g * 2 + par) * 256 + u) * 8 + n;
}

template<int CTRL>
__device__ __forceinline__ float dppadd(float x) {
    int v = __builtin_amdgcn_update_dpp(0, __float_as_int(x), CTRL, 0xF, 0xF, true);
    return x + __int_as_float(v);
}
// full 16-lane-row sum, result in every lane (2 quad_perm butterflies + 2 row rotations)
__device__ __forceinline__ float sum16(float x) {
    x = dppadd<0xB1>(x);    // quad_perm [1,0,3,2]  (xor 1)
    x = dppadd<0x4E>(x);    // quad_perm [2,3,0,1]  (xor 2)
    x = dppadd<0x124>(x);   // row_ror:4
    x = dppadd<0x128>(x);   // row_ror:8
    return x;
}

// h-row interleave: logical k -> padded index (breaks 64B-stride bank aliasing)
static __device__ __forceinline__ int kpad(int k) { return k + 4 * (k >> 4); }

// ---------------- prep: exchange slots <- (version 0, h0), both parities ----------------
__global__ void prep_kernel(const float* __restrict__ h0,
                            unsigned long long* __restrict__ xch) {
    int tid = blockIdx.x * blockDim.x + threadIdx.x;
    if (tid < B_SZ * H_SZ) {
        int b = tid >> 8, u = tid & 255;
        int g = b >> 3, n = b & 7;
        unsigned long long val = (unsigned long long)__float_as_uint(h0[tid]);
        xch[xsl(g, 0, u, n)] = val;
        xch[xsl(g, 1, u, n)] = val;
    }
}

// ---------------- phase 1: gx = x @ W_ih^T, pure f32 (unchanged) ----------------
__global__ __launch_bounds__(256) void gemm_x_kernel(
    const float* __restrict__ x, const float* __restrict__ wih,
    float* __restrict__ gx, int c, int tcShift)
{
    __shared__ __align__(16) float xs[64 * 128];
    const int TC = 1 << tcShift;
    const int t  = threadIdx.x;
    const int bx = blockIdx.x, by = blockIdx.y;

#pragma unroll
    for (int i = 0; i < 8; ++i) {
        int f4 = t + i * 256;
        int r  = f4 >> 5, c4 = f4 & 31;
        int rho = bx * 64 + r;
        int b = rho >> tcShift, u = rho & (TC - 1);
        float4 v = *(const float4*)(x + ((size_t)b * T_SZ + (size_t)c * TC + u) * 128 + c4 * 4);
        *(float4*)(xs + r * 128 + c4 * 4) = v;
    }
    __syncthreads();

    const int gl = (t & 31) * 4;
    const int rl = t >> 5;
    float acc[8][4];
#pragma unroll
    for (int i = 0; i < 8; ++i)
#pragma unroll
        for (int jj = 0; jj < 4; ++jj) acc[i][jj] = 0.f;

    const float* w0 = wih + (size_t)(by * 128 + gl) * 128;
#pragma unroll 4
    for (int k4 = 0; k4 < 32; ++k4) {
        float4 wv[4];
#pragma unroll
        for (int gi = 0; gi < 4; ++gi)
            wv[gi] = *(const float4*)(w0 + (size_t)gi * 128 + k4 * 4);
#pragma unroll
        for (int rr = 0; rr < 8; ++rr) {
            float4 xv = *(const float4*)(xs + (rl + rr * 8) * 128 + k4 * 4);
#pragma unroll
            for (int gi = 0; gi < 4; ++gi) {
                acc[rr][gi] = fmaf(xv.x, wv[gi].x,
                              fmaf(xv.y, wv[gi].y,
                              fmaf(xv.z, wv[gi].z,
                              fmaf(xv.w, wv[gi].w, acc[rr][gi]))));
            }
        }
    }
#pragma unroll
    for (int rr = 0; rr < 8; ++rr) {
        int rho = bx * 64 + rl + rr * 8;
        float4 o; o.x = acc[rr][0]; o.y = acc[rr][1]; o.z = acc[rr][2]; o.w = acc[rr][3];
        *(float4*)(gx + (size_t)rho * G3 + by * 128 + gl) = o;
    }
}

// ---------------- phase 2: LDS-weight recurrence, 8-way groups ----------------
// grid 256 x block 512. g = bid&31 (group), s = bid>>5 (unit slice) -> all 8 WGs of a
// group share bid mod 8 == g mod 8 -> same XCD under round-robin dispatch (perf only).
// Thread t: j = t>>4 (unit-local), p = t&15 (k-slice of 16). Lane rows of 16 = one j.
// LDS: Wl[96][260] f32 (rows q*32+j = whh row q*256+32s+j), hlb[2][8][320] (k-interleaved).
__global__ __launch_bounds__(512) void gru_kernel(
    const float* __restrict__ gx, const float* __restrict__ whh,
    const float* __restrict__ bih, const float* __restrict__ bhh,
    unsigned long long* __restrict__ xch, float* __restrict__ out,
    int gbase, int tc, int isLast)
{
    __shared__ __align__(16) float Wl[96][260];
    __shared__ __align__(16) float hlb[2][8][320];

    const int t   = threadIdx.x;
    const int bid = blockIdx.x;
    const int g   = bid & 31;
    const int s   = bid >> 5;
    const int u0  = s * 32;
    const int j   = t >> 4;
    const int p   = t & 15;
    const int uj  = u0 + j;

    // ---- W slice -> LDS (once; 96KB from L2) ----
#pragma unroll 4
    for (int i = t; i < 96 * 64; i += 512) {
        int r = i >> 6, c4 = (i & 63) * 4;
        int q = r >> 5, jl = r & 31;
        const float* src = whh + (size_t)(q * 256 + u0 + jl) * H_SZ + c4;
        float4 v = *(const float4*)src;
        Wl[r][c4] = v.x; Wl[r][c4 + 1] = v.y; Wl[r][c4 + 2] = v.z; Wl[r][c4 + 3] = v.w;
    }

    const float bsr = bih[uj]       + bhh[uj];
    const float bsz = bih[256 + uj] + bhh[256 + uj];
    const float bsn = bih[512 + uj] + bhh[512 + uj];

    // gx base for this thread's gate work (p<8 -> batch n=p)
    const float* gxp = nullptr;
    if (p < 8) gxp = gx + ((size_t)(8 * g + p) * tc) * G3 + uj;

    // ---- restore h(gbase) into hlb[0]: each thread polls 4 contiguous slots ----
    {
        const int par = gbase & 1;
        const unsigned want = (unsigned)gbase;
        unsigned long long* sb = xch + ((size_t)g * 2 + par) * 2048 + 4 * t;
        unsigned long long v0, v1, v2, v3;
        int spins = 0;
        for (;;) {
            v0 = __hip_atomic_load(sb + 0, __ATOMIC_RELAXED, __HIP_MEMORY_SCOPE_AGENT);
            v1 = __hip_atomic_load(sb + 1, __ATOMIC_RELAXED, __HIP_MEMORY_SCOPE_AGENT);
            v2 = __hip_atomic_load(sb + 2, __ATOMIC_RELAXED, __HIP_MEMORY_SCOPE_AGENT);
            v3 = __hip_atomic_load(sb + 3, __ATOMIC_RELAXED, __HIP_MEMORY_SCOPE_AGENT);
            bool ok = ((unsigned)(v0 >> 32) == want) & ((unsigned)(v1 >> 32) == want) &
                      ((unsigned)(v2 >> 32) == want) & ((unsigned)(v3 >> 32) == want);
            if (ok || ++spins >= SPIN_MAX) break;
            __builtin_amdgcn_s_sleep(2);
        }
        int i0 = 4 * t;
        hlb[0][(i0 + 0) & 7][kpad((i0 + 0) >> 3)] = __uint_as_float((unsigned)v0);
        hlb[0][(i0 + 1) & 7][kpad((i0 + 1) >> 3)] = __uint_as_float((unsigned)v1);
        hlb[0][(i0 + 2) & 7][kpad((i0 + 2) >> 3)] = __uint_as_float((unsigned)v2);
        hlb[0][(i0 + 3) & 7][kpad((i0 + 3) >> 3)] = __uint_as_float((unsigned)v3);
    }
    __syncthreads();

    int cur = 0;
#pragma unroll 1
    for (int u = 0; u < tc; ++u) {
        const int tg = gbase + u;
        // gx for this step (issued now, consumed after matvec+reduce)
        float gxr = 0.f, gxz = 0.f, gxn = 0.f;
        if (p < 8) {
            size_t go = (size_t)u * G3;
            gxr = gxp[go]; gxz = gxp[go + 256]; gxn = gxp[go + 512];
        }

        // ---- matvec: acc[q][n] += W[q*32+j][k-slice] . h[n][k-slice] ----
        float acc[3][8];
#pragma unroll
        for (int q = 0; q < 3; ++q)
#pragma unroll
            for (int n = 0; n < 8; ++n) acc[q][n] = 0.f;

        const float* hb = &hlb[cur][0][0];
#pragma unroll
        for (int c = 0; c < 4; ++c) {
            const int ko = p * 16 + c * 4;        // W column
            const int hp = p * 20 + c * 4;        // h padded column
            float4 w0 = *(const float4*)&Wl[j][ko];
            float4 w1 = *(const float4*)&Wl[32 + j][ko];
            float4 w2 = *(const float4*)&Wl[64 + j][ko];
#pragma unroll
            for (int n = 0; n < 8; ++n) {
                float4 hv = *(const float4*)(hb + n * 320 + hp);
                acc[0][n] = fmaf(w0.w, hv.w, fmaf(w0.z, hv.z, fmaf(w0.y, hv.y, fmaf(w0.x, hv.x, acc[0][n]))));
                acc[1][n] = fmaf(w1.w, hv.w, fmaf(w1.z, hv.z, fmaf(w1.y, hv.y, fmaf(w1.x, hv.x, acc[1][n]))));
                acc[2][n] = fmaf(w2.w, hv.w, fmaf(w2.z, hv.z, fmaf(w2.y, hv.y, fmaf(w2.x, hv.x, acc[2][n]))));
            }
        }

        // ---- 16-lane DPP reduce; keep the (q, n==p) triple ----
        float sr = 0.f, sz = 0.f, sn = 0.f;
#pragma unroll
        for (int n = 0; n < 8; ++n) {
            float v0 = sum16(acc[0][n]);
            float v1 = sum16(acc[1][n]);
            float v2 = sum16(acc[2][n]);
            if (p == n) { sr = v0; sz = v1; sn = v2; }
        }

        // ---- gates + publish (threads p<8, batch n=p) ----
        if (p < 8) {
            const int n = p;
            float hold = hlb[cur][n][kpad(uj)];
            float ar = sr + gxr + bsr;
            float az = sz + gxz + bsz;
            float an = sn + gxn + bsn;
            float r  = 1.f / (1.f + expf(-ar));
            float z  = 1.f / (1.f + expf(-az));
            float nn = tanhf(r * an);
            float hn = (1.f - z) * hold + z * nn;

            size_t o0 = ((size_t)(8 * g + n) * T_SZ + tg) * H_SZ + uj;
            out[o0] = hn;
            if (isLast && u == tc - 1)
                out[(size_t)B_SZ * T_SZ * H_SZ + (size_t)(8 * g + n) * H_SZ + uj] = hn;

            const unsigned long long pv =
                ((unsigned long long)(unsigned)(tg + 1) << 32) |
                (unsigned long long)__float_as_uint(hn);
            __hip_atomic_store(xch + xsl(g, (tg + 1) & 1, uj, n), pv,
                               __ATOMIC_RELAXED, __HIP_MEMORY_SCOPE_AGENT);
        }

        // ---- gather h(tg+1) for next step from all 8 WGs of the group ----
        if (u + 1 < tc) {
            const int nb = cur ^ 1;
            const int par = (tg + 1) & 1;
            const unsigned want = (unsigned)(tg + 1);
            unsigned long long* sb = xch + ((size_t)g * 2 + par) * 2048 + 4 * t;
            unsigned long long v0, v1, v2, v3;
            int spins = 0;
            for (;;) {
                v0 = __hip_atomic_load(sb + 0, __ATOMIC_RELAXED, __HIP_MEMORY_SCOPE_AGENT);
                v1 = __hip_atomic_load(sb + 1, __ATOMIC_RELAXED, __HIP_MEMORY_SCOPE_AGENT);
                v2 = __hip_atomic_load(sb + 2, __ATOMIC_RELAXED, __HIP_MEMORY_SCOPE_AGENT);
                v3 = __hip_atomic_load(sb + 3, __ATOMIC_RELAXED, __HIP_MEMORY_SCOPE_AGENT);
                bool ok = ((unsigned)(v0 >> 32) == want) & ((unsigned)(v1 >> 32) == want) &
                          ((unsigned)(v2 >> 32) == want) & ((unsigned)(v3 >> 32) == want);
                if (ok || ++spins >= SPIN_MAX) break;
                __builtin_amdgcn_s_sleep(2);
            }
            int i0 = 4 * t;
            hlb[nb][(i0 + 0) & 7][kpad((i0 + 0) >> 3)] = __uint_as_float((unsigned)v0);
            hlb[nb][(i0 + 1) & 7][kpad((i0 + 1) >> 3)] = __uint_as_float((unsigned)v1);
            hlb[nb][(i0 + 2) & 7][kpad((i0 + 2) >> 3)] = __uint_as_float((unsigned)v2);
            hlb[nb][(i0 + 3) & 7][kpad((i0 + 3) >> 3)] = __uint_as_float((unsigned)v3);
            __syncthreads();
            cur = nb;
        }
    }
}

// ---------------- host ----------------
extern "C" void kernel_launch(void* const* d_in, const int* in_sizes, int n_in,
                              void* d_out, int out_size, void* d_ws, size_t ws_size,
                              hipStream_t stream) {
    const float* x   = (const float*)d_in[0];
    const float* h0  = (const float*)d_in[1];
    const float* wih = (const float*)d_in[2];
    const float* whh = (const float*)d_in[3];
    const float* bih = (const float*)d_in[4];
    const float* bhh = (const float*)d_in[5];
    float* out = (float*)d_out;

    char* ws = (char*)d_ws;
    const size_t xchB = (size_t)NGRP * 2 * 256 * 8 * 8;   // 1 MiB
    unsigned long long* xch = (unsigned long long*)ws;
    float* gxb = (float*)(ws + xchB);

    int tcShift = 10;
    while (tcShift > 0 &&
           xchB + ((size_t)G3 * 4 * B_SZ << tcShift) > ws_size) --tcShift;
    const int TC  = 1 << tcShift;
    const int nCh = T_SZ / TC;

    prep_kernel<<<dim3(256), dim3(256), 0, stream>>>(h0, xch);
    for (int c = 0; c < nCh; ++c) {
        gemm_x_kernel<<<dim3(B_SZ * TC / 64, 6), dim3(256), 0, stream>>>(
            x, wih, gxb, c, tcShift);
        gru_kernel<<<dim3(B_SZ), dim3(512), 0, stream>>>(
            gxb, whh, bih, bhh, xch, out, c * TC, TC, (c == nCh - 1) ? 1 : 0);
    }
}

// Round 9
// 4782.381 us; speedup vs baseline: 1.4650x; 1.2565x over previous
//
#include <hip/hip_runtime.h>

// CustomGRU: B=256, T=1024, I=128, H=256.  out = concat(output[B,T,H], h_last[B,H]) f32.
//
// R9: (a) gru: W_hh slice per thread = 48 f32 (12 named float4, asm-pinned) in
// registers -- small enough for any RA budget; LDS holds ONLY h (kpad layout, 20KB).
// Kills R8's 1.47e8 LDS bank conflicts (W stride-16 reads were ~8-way).
// (b) gemm: wih staged in LDS per 64-k half; inner loop pure LDS+FMA (VALU-bound).
// Exchange protocol (parity-double-buffered version slots, 8-WG groups) unchanged.

#define B_SZ 256
#define T_SZ 1024
#define H_SZ 256
#define G3   768
#define NGRP 32
#define SPIN_MAX (1 << 27)

static __device__ __forceinline__ size_t xsl(int g, int par, int u, int n) {
    return (((size_t)g * 2 + par) * 256 + u) * 8 + n;
}

template<int CTRL>
__device__ __forceinline__ float dppadd(float x) {
    int v = __builtin_amdgcn_update_dpp(0, __float_as_int(x), CTRL, 0xF, 0xF, true);
    return x + __int_as_float(v);
}
__device__ __forceinline__ float sum16(float x) {
    x = dppadd<0xB1>(x);    // quad_perm xor1
    x = dppadd<0x4E>(x);    // quad_perm xor2
    x = dppadd<0x124>(x);   // row_ror:4
    x = dppadd<0x128>(x);   // row_ror:8
    return x;
}

static __device__ __forceinline__ int kpad(int k) { return k + 4 * (k >> 4); }

// ---------------- prep ----------------
__global__ void prep_kernel(const float* __restrict__ h0,
                            unsigned long long* __restrict__ xch) {
    int tid = blockIdx.x * blockDim.x + threadIdx.x;
    if (tid < B_SZ * H_SZ) {
        int b = tid >> 8, u = tid & 255;
        int g = b >> 3, n = b & 7;
        unsigned long long val = (unsigned long long)__float_as_uint(h0[tid]);
        xch[xsl(g, 0, u, n)] = val;
        xch[xsl(g, 1, u, n)] = val;
    }
}

// ---------------- phase 1: gx = x @ W_ih^T, LDS-staged both operands ----------------
// grid (B*TC/64, 6), block 256. Tile: 64 rho x 128 g, K=128 in two 64-k halves.
// Thread: rl = t>>5 (8 rows stride 8), gl = t&31; cols gl + 32*gi (gi 0..3).
__global__ __launch_bounds__(256) void gemm_x_kernel(
    const float* __restrict__ x, const float* __restrict__ wih,
    float* __restrict__ gx, int c, int tcShift)
{
    __shared__ __align__(16) float xs[64][132];
    __shared__ __align__(16) float ws[128][68];
    const int TC = 1 << tcShift;
    const int t  = threadIdx.x;
    const int bx = blockIdx.x, by = blockIdx.y;

    // stage x tile once (full K)
#pragma unroll
    for (int i = 0; i < 8; ++i) {
        int f4 = t + i * 256;
        int r  = f4 >> 5, c4 = (f4 & 31) * 4;
        int rho = bx * 64 + r;
        int b = rho >> tcShift, u = rho & (TC - 1);
        float4 v = *(const float4*)(x + ((size_t)b * T_SZ + (size_t)c * TC + u) * 128 + c4);
        *(float4*)&xs[r][c4] = v;
    }

    const int gl = t & 31;
    const int rl = t >> 5;
    float acc[8][4];
#pragma unroll
    for (int i = 0; i < 8; ++i)
#pragma unroll
        for (int jj = 0; jj < 4; ++jj) acc[i][jj] = 0.f;

    for (int kb = 0; kb < 2; ++kb) {
        __syncthreads();   // xs visible (kb=0); prior ws fully consumed (kb=1)
        // stage ws: 128 g-rows x 64 k
#pragma unroll
        for (int i = 0; i < 8; ++i) {
            int f4 = t + i * 256;
            int row = f4 >> 4, c4 = (f4 & 15) * 4;
            float4 v = *(const float4*)(wih + (size_t)(by * 128 + row) * 128 + kb * 64 + c4);
            *(float4*)&ws[row][c4] = v;
        }
        __syncthreads();

#pragma unroll 4
        for (int k4 = 0; k4 < 16; ++k4) {
            float4 wv0 = *(const float4*)&ws[gl     ][k4 * 4];
            float4 wv1 = *(const float4*)&ws[gl + 32][k4 * 4];
            float4 wv2 = *(const float4*)&ws[gl + 64][k4 * 4];
            float4 wv3 = *(const float4*)&ws[gl + 96][k4 * 4];
#pragma unroll
            for (int rr = 0; rr < 8; ++rr) {
                float4 xv = *(const float4*)&xs[rl + rr * 8][kb * 64 + k4 * 4];
                acc[rr][0] = fmaf(xv.w, wv0.w, fmaf(xv.z, wv0.z, fmaf(xv.y, wv0.y, fmaf(xv.x, wv0.x, acc[rr][0]))));
                acc[rr][1] = fmaf(xv.w, wv1.w, fmaf(xv.z, wv1.z, fmaf(xv.y, wv1.y, fmaf(xv.x, wv1.x, acc[rr][1]))));
                acc[rr][2] = fmaf(xv.w, wv2.w, fmaf(xv.z, wv2.z, fmaf(xv.y, wv2.y, fmaf(xv.x, wv2.x, acc[rr][2]))));
                acc[rr][3] = fmaf(xv.w, wv3.w, fmaf(xv.z, wv3.z, fmaf(xv.y, wv3.y, fmaf(xv.x, wv3.x, acc[rr][3]))));
            }
        }
    }

#pragma unroll
    for (int rr = 0; rr < 8; ++rr) {
        size_t base = (size_t)(bx * 64 + rl + rr * 8) * G3 + by * 128 + gl;
#pragma unroll
        for (int gi = 0; gi < 4; ++gi)
            gx[base + 32 * gi] = acc[rr][gi];
    }
}

// ---- 16-elem dot of a thread's W slice vs one h row (all float4, static) ----
__device__ __forceinline__ float d16(float a,
    const float4& W0, const float4& W1, const float4& W2, const float4& W3,
    const float4& H0, const float4& H1, const float4& H2, const float4& H3) {
    a = fmaf(W0.x, H0.x, a); a = fmaf(W0.y, H0.y, a); a = fmaf(W0.z, H0.z, a); a = fmaf(W0.w, H0.w, a);
    a = fmaf(W1.x, H1.x, a); a = fmaf(W1.y, H1.y, a); a = fmaf(W1.z, H1.z, a); a = fmaf(W1.w, H1.w, a);
    a = fmaf(W2.x, H2.x, a); a = fmaf(W2.y, H2.y, a); a = fmaf(W2.z, H2.z, a); a = fmaf(W2.w, H2.w, a);
    a = fmaf(W3.x, H3.x, a); a = fmaf(W3.y, H3.y, a); a = fmaf(W3.z, H3.z, a); a = fmaf(W3.w, H3.w, a);
    return a;
}

#define PIN4(v) asm volatile("" : "+v"(v.x), "+v"(v.y), "+v"(v.z), "+v"(v.w));

// ---------------- phase 2: recurrence; W slice in registers, h in LDS ----------------
// grid 256 x 512. g = bid&31 (group), s = bid>>5. Thread: j = t>>4 (unit), p = t&15
// (16-k slice). W regs: 3 gates x 4 float4 = 48 f32. LDS: hlb[2][8][320] only.
__global__ __launch_bounds__(512)
__attribute__((amdgpu_waves_per_eu(2, 2)))
void gru_kernel(
    const float* __restrict__ gx, const float* __restrict__ whh,
    const float* __restrict__ bih, const float* __restrict__ bhh,
    unsigned long long* __restrict__ xch, float* __restrict__ out,
    int gbase, int tc, int isLast)
{
    __shared__ __align__(16) float hlb[2][8][320];

    const int t   = threadIdx.x;
    const int bid = blockIdx.x;
    const int g   = bid & 31;
    const int s   = bid >> 5;
    const int u0  = s * 32;
    const int j   = t >> 4;
    const int p   = t & 15;
    const int uj  = u0 + j;

    // ---- W slice -> 12 named float4 registers ----
    const float* wr0 = whh + (size_t)(uj)       * H_SZ + p * 16;
    const float* wr1 = whh + (size_t)(256 + uj) * H_SZ + p * 16;
    const float* wr2 = whh + (size_t)(512 + uj) * H_SZ + p * 16;
    float4 w00 = *(const float4*)(wr0 + 0), w01 = *(const float4*)(wr0 + 4),
           w02 = *(const float4*)(wr0 + 8), w03 = *(const float4*)(wr0 + 12);
    float4 w10 = *(const float4*)(wr1 + 0), w11 = *(const float4*)(wr1 + 4),
           w12 = *(const float4*)(wr1 + 8), w13 = *(const float4*)(wr1 + 12);
    float4 w20 = *(const float4*)(wr2 + 0), w21 = *(const float4*)(wr2 + 4),
           w22 = *(const float4*)(wr2 + 8), w23 = *(const float4*)(wr2 + 12);
    PIN4(w00) PIN4(w01) PIN4(w02) PIN4(w03)
    PIN4(w10) PIN4(w11) PIN4(w12) PIN4(w13)
    PIN4(w20) PIN4(w21) PIN4(w22) PIN4(w23)

    const float bsr = bih[uj]       + bhh[uj];
    const float bsz = bih[256 + uj] + bhh[256 + uj];
    const float bsn = bih[512 + uj] + bhh[512 + uj];

    const float* gxp = nullptr;
    if (p < 8) gxp = gx + ((size_t)(8 * g + p) * tc) * G3 + uj;

    // ---- restore h(gbase) into hlb[0] ----
    {
        const int par = gbase & 1;
        const unsigned want = (unsigned)gbase;
        unsigned long long* sb = xch + ((size_t)g * 2 + par) * 2048 + 4 * t;
        unsigned long long v0, v1, v2, v3;
        int spins = 0;
        for (;;) {
            v0 = __hip_atomic_load(sb + 0, __ATOMIC_RELAXED, __HIP_MEMORY_SCOPE_AGENT);
            v1 = __hip_atomic_load(sb + 1, __ATOMIC_RELAXED, __HIP_MEMORY_SCOPE_AGENT);
            v2 = __hip_atomic_load(sb + 2, __ATOMIC_RELAXED, __HIP_MEMORY_SCOPE_AGENT);
            v3 = __hip_atomic_load(sb + 3, __ATOMIC_RELAXED, __HIP_MEMORY_SCOPE_AGENT);
            bool ok = ((unsigned)(v0 >> 32) == want) & ((unsigned)(v1 >> 32) == want) &
                      ((unsigned)(v2 >> 32) == want) & ((unsigned)(v3 >> 32) == want);
            if (ok || ++spins >= SPIN_MAX) break;
            __builtin_amdgcn_s_sleep(2);
        }
        int i0 = 4 * t;
        hlb[0][(i0 + 0) & 7][kpad((i0 + 0) >> 3)] = __uint_as_float((unsigned)v0);
        hlb[0][(i0 + 1) & 7][kpad((i0 + 1) >> 3)] = __uint_as_float((unsigned)v1);
        hlb[0][(i0 + 2) & 7][kpad((i0 + 2) >> 3)] = __uint_as_float((unsigned)v2);
        hlb[0][(i0 + 3) & 7][kpad((i0 + 3) >> 3)] = __uint_as_float((unsigned)v3);
    }
    __syncthreads();

    int cur = 0;
#pragma unroll 1
    for (int u = 0; u < tc; ++u) {
        const int tg = gbase + u;
        float gxr = 0.f, gxz = 0.f, gxn = 0.f;
        if (p < 8) {
            size_t go = (size_t)u * G3;
            gxr = gxp[go]; gxz = gxp[go + 256]; gxn = gxp[go + 512];
        }

        // ---- matvec over 8 batch rows; W in regs, h from LDS (broadcast/2-way) ----
        float acc0[8], acc1[8], acc2[8];
        const float* hbp = &hlb[cur][0][0] + p * 20;
#pragma unroll
        for (int n = 0; n < 8; ++n) {
            const float* hr = hbp + n * 320;
            float4 h0 = *(const float4*)(hr);
            float4 h1 = *(const float4*)(hr + 4);
            float4 h2 = *(const float4*)(hr + 8);
            float4 h3 = *(const float4*)(hr + 12);
            acc0[n] = d16(0.f, w00, w01, w02, w03, h0, h1, h2, h3);
            acc1[n] = d16(0.f, w10, w11, w12, w13, h0, h1, h2, h3);
            acc2[n] = d16(0.f, w20, w21, w22, w23, h0, h1, h2, h3);
        }

        // ---- 16-lane reduce; keep the n==p triple ----
        float sr = 0.f, sz = 0.f, sn = 0.f;
#pragma unroll
        for (int n = 0; n < 8; ++n) {
            float v0 = sum16(acc0[n]);
            float v1 = sum16(acc1[n]);
            float v2 = sum16(acc2[n]);
            if (p == n) { sr = v0; sz = v1; sn = v2; }
        }

        // ---- gates + publish (p<8, batch n=p); publish FIRST, out store after ----
        if (p < 8) {
            const int n = p;
            float hold = hlb[cur][n][kpad(uj)];
            float ar = sr + gxr + bsr;
            float az = sz + gxz + bsz;
            float an = sn + gxn + bsn;
            float r  = 1.f / (1.f + expf(-ar));
            float z  = 1.f / (1.f + expf(-az));
            float nn = tanhf(r * an);
            float hn = (1.f - z) * hold + z * nn;

            const unsigned long long pv =
                ((unsigned long long)(unsigned)(tg + 1) << 32) |
                (unsigned long long)__float_as_uint(hn);
            __hip_atomic_store(xch + xsl(g, (tg + 1) & 1, uj, n), pv,
                               __ATOMIC_RELAXED, __HIP_MEMORY_SCOPE_AGENT);

            size_t o0 = ((size_t)(8 * g + n) * T_SZ + tg) * H_SZ + uj;
            out[o0] = hn;
            if (isLast && u == tc - 1)
                out[(size_t)B_SZ * T_SZ * H_SZ + (size_t)(8 * g + n) * H_SZ + uj] = hn;
        }

        // ---- gather h(tg+1) ----
        if (u + 1 < tc) {
            const int nb = cur ^ 1;
            const int par = (tg + 1) & 1;
            const unsigned want = (unsigned)(tg + 1);
            unsigned long long* sb = xch + ((size_t)g * 2 + par) * 2048 + 4 * t;
            unsigned long long v0, v1, v2, v3;
            int spins = 0;
            for (;;) {
                v0 = __hip_atomic_load(sb + 0, __ATOMIC_RELAXED, __HIP_MEMORY_SCOPE_AGENT);
                v1 = __hip_atomic_load(sb + 1, __ATOMIC_RELAXED, __HIP_MEMORY_SCOPE_AGENT);
                v2 = __hip_atomic_load(sb + 2, __ATOMIC_RELAXED, __HIP_MEMORY_SCOPE_AGENT);
                v3 = __hip_atomic_load(sb + 3, __ATOMIC_RELAXED, __HIP_MEMORY_SCOPE_AGENT);
                bool ok = ((unsigned)(v0 >> 32) == want) & ((unsigned)(v1 >> 32) == want) &
                          ((unsigned)(v2 >> 32) == want) & ((unsigned)(v3 >> 32) == want);
                if (ok || ++spins >= SPIN_MAX) break;
                __builtin_amdgcn_s_sleep(2);
            }
            int i0 = 4 * t;
            hlb[nb][(i0 + 0) & 7][kpad((i0 + 0) >> 3)] = __uint_as_float((unsigned)v0);
            hlb[nb][(i0 + 1) & 7][kpad((i0 + 1) >> 3)] = __uint_as_float((unsigned)v1);
            hlb[nb][(i0 + 2) & 7][kpad((i0 + 2) >> 3)] = __uint_as_float((unsigned)v2);
            hlb[nb][(i0 + 3) & 7][kpad((i0 + 3) >> 3)] = __uint_as_float((unsigned)v3);
            __syncthreads();
            cur = nb;
        }
    }
}

// ---------------- host ----------------
extern "C" void kernel_launch(void* const* d_in, const int* in_sizes, int n_in,
                              void* d_out, int out_size, void* d_ws, size_t ws_size,
                              hipStream_t stream) {
    const float* x   = (const float*)d_in[0];
    const float* h0  = (const float*)d_in[1];
    const float* wih = (const float*)d_in[2];
    const float* whh = (const float*)d_in[3];
    const float* bih = (const float*)d_in[4];
    const float* bhh = (const float*)d_in[5];
    float* out = (float*)d_out;

    char* ws = (char*)d_ws;
    const size_t xchB = (size_t)NGRP * 2 * 256 * 8 * 8;   // 1 MiB
    unsigned long long* xch = (unsigned long long*)ws;
    float* gxb = (float*)(ws + xchB);

    int tcShift = 10;
    while (tcShift > 0 &&
           xchB + ((size_t)G3 * 4 * B_SZ << tcShift) > ws_size) --tcShift;
    const int TC  = 1 << tcShift;
    const int nCh = T_SZ / TC;

    prep_kernel<<<dim3(256), dim3(256), 0, stream>>>(h0, xch);
    for (int c = 0; c < nCh; ++c) {
        gemm_x_kernel<<<dim3(B_SZ * TC / 64, 6), dim3(256), 0, stream>>>(
            x, wih, gxb, c, tcShift);
        gru_kernel<<<dim3(B_SZ), dim3(512), 0, stream>>>(
            gxb, whh, bih, bhh, xch, out, c * TC, TC, (c == nCh - 1) ? 1 : 0);
    }
}